// Round 13
// baseline (146.323 us; speedup 1.0000x reference)
//
#include <hip/hip_runtime.h>
#include <hip/hip_bf16.h>

typedef unsigned short u16;
typedef __attribute__((ext_vector_type(8))) short short8;
typedef __attribute__((ext_vector_type(16))) float f32x16;

#define HID 128
#define WNUMEL 3072
#define OUTD 144

// ---------- fused pre-pass: W2 swizzle(32x32 frags) | MLP | linked-list build ----------
__global__ void k_pre(const float* __restrict__ W2, __hip_bfloat16* __restrict__ W2s,
                      const float* __restrict__ es, const float* __restrict__ W1,
                      const float* __restrict__ b1, __hip_bfloat16* __restrict__ h2s,
                      const int* __restrict__ dst, int* __restrict__ head,
                      int* __restrict__ nxt, int E, int NW, int NM) {
  __shared__ float esl[8][32];
  const int b = blockIdx.x, tid = threadIdx.x;
  if (b < NW) {
    // W2 -> bf16, 32x32x16 B-fragment layout, float4-vectorized read
    // frag(ntg,ks): lane l, i: element W2[ks*16+(l>>5)*8+i][ntg*32+(l&31)]
    // dest(k,n) = ((n>>5)*8 + (k>>4))*512 + ((n&31)+32*((k>>3)&1))*8 + (k&7)
    int t = b * 256 + tid;                 // < 128*3072/4 = 98304
    int k = t / 768, n4 = (t - k * 768) * 4;
    const float4 w4 = *(const float4*)(W2 + (size_t)k * WNUMEL + n4);
    int base = ((n4 >> 5) * 8 + (k >> 4)) * 512 + 32 * ((k >> 3) & 1) * 8 + (k & 7);
#pragma unroll
    for (int j = 0; j < 4; ++j)
      W2s[base + ((n4 & 31) + j) * 8] = __float2bfloat16((&w4.x)[j]);
  } else if (b < NW + NM) {
    // MLP: h2 = silu(es@W1+b1)*0.125, stored in 32x32x16 A-fragment layout
    int e0 = (b - NW) * 8;
    {
      int e = e0 + (tid >> 5);
      esl[tid >> 5][tid & 31] = (e < E) ? es[e * 32 + (tid & 31)] : 0.f;
    }
    __syncthreads();
    int h = tid & 127;
    float bh = b1[h];
    float w1c[32];
#pragma unroll
    for (int i = 0; i < 32; ++i) w1c[i] = W1[i * HID + h];
#pragma unroll
    for (int r = 0; r < 4; ++r) {
      int eloc = (tid >> 7) + r * 2;
      int e = e0 + eloc;
      if (e < E) {
        float acc = bh;
#pragma unroll
        for (int i = 0; i < 32; ++i) acc = fmaf(esl[eloc][i], w1c[i], acc);
        float sg = 1.f / (1.f + expf(-acc));
        float z = acc * sg * 0.125f;       // fold 1/sqrt(64)
        // dest(e,h) = ((e>>5)*8 + (h>>4))*512 + ((e&31)+32*((h>>3)&1))*8 + (h&7)
        h2s[((size_t)(e >> 5) * 8 + (h >> 4)) * 512 +
            ((e & 31) + 32 * ((h >> 3) & 1)) * 8 + (h & 7)] = __float2bfloat16(z);
      }
    }
  } else {
    int e = (b - NW - NM) * 256 + tid;
    if (e < E) nxt[e] = atomicExch(&head[dst[e]], e);   // per-dst linked list
  }
}

// ---------- fused GEMM (32x32x16) + x-contraction -> feat[E][48] ----------
// grid = (E/64, 3). Block = 64 edges (2 M-tiles of 32) x one l-path (32 N-tiles
// of 32). Wave owns 8 N-tiles x 2 mt x 8 k-steps = 128 MFMA. 32x32x16 halves
// the L1 port traffic per FLOP vs 16x16x32 (the R6-R12 wall): A/B fragment
// bytes per instruction unchanged but 2x FLOP each. C-layout (HW-verified):
// col=lane&31, row=(reg&3)+8*(reg>>2)+4*(lane>>5). A/B share one k-bijection
// (k = ks*16 + (lane>>5)*8 + i) -> layout-safe.
__global__ __launch_bounds__(256, 2) void k_gemm(
    const u16* __restrict__ h2s, const u16* __restrict__ W2s,
    const float* __restrict__ hsrc, const int* __restrict__ srci,
    const float* __restrict__ b2, float* __restrict__ feat_out, int E) {
  __shared__ float lds[4160];          // xT[64u][64e] (16KB) then fl[4][1040]
  const int tid = threadIdx.x, lane = tid & 63, wave = tid >> 6;
  const int blk = blockIdx.x, l3 = blockIdx.y;
  const int col = lane & 31;           // C column within 32-tile
  const int half = lane >> 5;          // row-group select
  const int upar = (lane >> 4) & 1;    // u parity within N-tile
  const int v = lane & 15;

  // stage x transposed (wave w stages u-rows [w*16, w*16+16))
  {
    int e = lane, u0 = wave * 16;
    int eg = min(blk * 64 + e, E - 1);
    const float* xr = hsrc + (size_t)srci[eg] * 64 + u0;
#pragma unroll
    for (int k = 0; k < 16; ++k) lds[(u0 + k) * 64 + e] = xr[k];
  }
  __syncthreads();

  float fr[2][16] = {};                // feat partials [mt][reg]

#pragma unroll
  for (int q = 0; q < 8; ++q) {        // wave's 8 N-tiles
    const int ntg = l3 * 32 + wave * 8 + q;
    const float b2v = 0.125f * b2[ntg * 32 + col];
    f32x16 accA, accB;
#pragma unroll
    for (int r = 0; r < 16; ++r) { accA[r] = b2v; accB[r] = b2v; }
#pragma unroll
    for (int ks = 0; ks < 8; ++ks) {
      short8 bf = *(const short8*)(W2s + ((size_t)ntg * 8 + ks) * 512 + lane * 8);
      short8 a0 = *(const short8*)(h2s + ((size_t)(blk * 2 + 0) * 8 + ks) * 512 + lane * 8);
      accA = __builtin_amdgcn_mfma_f32_32x32x16_bf16(a0, bf, accA, 0, 0, 0);
      short8 a1 = *(const short8*)(h2s + ((size_t)(blk * 2 + 1) * 8 + ks) * 512 + lane * 8);
      accB = __builtin_amdgcn_mfma_f32_32x32x16_bf16(a1, bf, accB, 0, 0, 0);
    }
    // x-contraction: lane's col -> (u, v); rows in 4 contiguous quads
    const int ul = (wave * 8 + q) * 2 + upar;
    const float* xb = &lds[ul * 64];
#pragma unroll
    for (int rg = 0; rg < 4; ++rg) {
      const int rbase = 8 * (rg & 1) + 16 * (rg >> 1);   // rows rbase+4*half ..+3
      const float4 x0 = *(const float4*)(xb + rbase + 4 * half);
      const float4 x1 = *(const float4*)(xb + 32 + rbase + 4 * half);
#pragma unroll
      for (int j = 0; j < 4; ++j) {
        // reg index: r with (r>>2)==rg2? rows: (r&3)+8*(r>>2)+4*half
        // choose r such that 8*(r>>2) == rbase -> r = rg2*4+j with rg2 = rg? see map below
        fr[0][((rg & 1) ? 4 : 0) + ((rg >> 1) ? 8 : 0) + j] =
            fmaf((&x0.x)[j], accA[((rg & 1) ? 4 : 0) + ((rg >> 1) ? 8 : 0) + j],
                 fr[0][((rg & 1) ? 4 : 0) + ((rg >> 1) ? 8 : 0) + j]);
        fr[1][((rg & 1) ? 4 : 0) + ((rg >> 1) ? 8 : 0) + j] =
            fmaf((&x1.x)[j], accB[((rg & 1) ? 4 : 0) + ((rg >> 1) ? 8 : 0) + j],
                 fr[1][((rg & 1) ? 4 : 0) + ((rg >> 1) ? 8 : 0) + j]);
      }
    }
  }
  // reduce u-parity pairs (lane ^ 16 has same rows/v, other u)
#pragma unroll
  for (int mt = 0; mt < 2; ++mt)
#pragma unroll
    for (int r = 0; r < 16; ++r)
      fr[mt][r] += __shfl_xor(fr[mt][r], 16, 64);

  __syncthreads();                     // xT no longer needed; overlay fl
  if (upar == 0) {
#pragma unroll
    for (int mt = 0; mt < 2; ++mt)
#pragma unroll
      for (int r = 0; r < 16; ++r) {
        int row = (r & 3) + 8 * (r >> 2) + 4 * half + 32 * mt;
        lds[wave * 1040 + row * 16 + v] = fr[mt][r];
      }
  }
  __syncthreads();

  // epilogue: sum the 4 wave-partials (u-ranges), store compact feat
#pragma unroll
  for (int r = 0; r < 4; ++r) {
    int p = r * 256 + tid;             // 1024 = 64 edges x 16 v
    int eloc = p >> 4, vv = p & 15;
    float f = lds[p] + lds[1040 + p] + lds[2080 + p] + lds[3120 + p];
    int e = blk * 64 + eloc;
    if (e < E) feat_out[(size_t)e * 48 + l3 * 16 + vv] = f;
  }
}

// ---------- gather: wave per dst; walk list; inline sh; mean ----------
__device__ __forceinline__ float shv(int idx, float x, float y, float z) {
  const float SQ3 = 1.7320508075688772f, SQ5 = 2.2360679774997896f,
              SQ15 = 3.872983346207417f;
  switch (idx) {
    case 0: return 1.f;
    case 1: return SQ3 * x;
    case 2: return SQ3 * y;
    case 3: return SQ3 * z;
    case 4: return SQ15 * x * y;
    case 5: return SQ15 * y * z;
    case 6: return 0.5f * SQ5 * (3.f * z * z - 1.f);
    case 7: return SQ15 * x * z;
    default: return 0.5f * SQ15 * (x * x - y * y);
  }
}

__global__ void k_gather(const float* __restrict__ feat, const float* __restrict__ ev,
                         const int* __restrict__ head, const int* __restrict__ nxt,
                         float* __restrict__ out, int n_dst) {
  int d = blockIdx.x * 4 + (threadIdx.x >> 6);
  int lane = threadIdx.x & 63;
  if (d >= n_dst) return;
  int fi[4], si[4];
#pragma unroll
  for (int r = 0; r < 4; ++r) {
    int o = lane * 4 + r;
    if (o < 16)      { fi[r] = o;                 si[r] = 0; }
    else if (o < 64) { int id = o - 16; fi[r] = 16 + id / 3; si[r] = 1 + id % 3; }
    else             { int id = o - 64; fi[r] = 32 + id / 5; si[r] = 4 + id % 5; }
  }
  int e = head[d];
  float4 acc = {0.f, 0.f, 0.f, 0.f};
  int deg = 0;
  while (e >= 0) {
    int en = nxt[e];                   // issue next hop first
    if (lane < 36) {
      float vx = ev[e * 3 + 0], vy = ev[e * 3 + 1], vz = ev[e * 3 + 2];
      float nrm = fmaxf(sqrtf(vx * vx + vy * vy + vz * vz), 1e-9f);
      float x = vx / nrm, y = vy / nrm, z = vz / nrm;
      const float* fp = feat + (size_t)e * 48;
#pragma unroll
      for (int r = 0; r < 4; ++r)
        (&acc.x)[r] = fmaf(fp[fi[r]], shv(si[r], x, y, z), (&acc.x)[r]);
    }
    ++deg;
    e = en;
  }
  if (lane < 36) {
    float inv = 1.f / (float)max(deg, 1);
    acc.x *= inv; acc.y *= inv; acc.z *= inv; acc.w *= inv;
    *(float4*)&out[(size_t)d * OUTD + lane * 4] = acc;
  }
}

extern "C" void kernel_launch(void* const* d_in, const int* in_sizes, int n_in,
                              void* d_out, int out_size, void* d_ws, size_t ws_size,
                              hipStream_t stream) {
  const float* h_src        = (const float*)d_in[0];
  const float* edge_vec     = (const float*)d_in[1];
  const float* edge_scalars = (const float*)d_in[2];
  const float* W1           = (const float*)d_in[3];
  const float* b1           = (const float*)d_in[4];
  const float* W2           = (const float*)d_in[5];
  const float* b2           = (const float*)d_in[6];
  const int*   src_idx      = (const int*)d_in[7];
  const int*   dst_idx      = (const int*)d_in[8];

  const int E = in_sizes[1] / 3;
  const int n_dst = out_size / OUTD;
  const int nblk64 = (E + 63) / 64;
  const size_t E_pad = (size_t)nblk64 * 64;

  char* w = (char*)d_ws;
  auto al = [](size_t x) { return (x + 255) & ~(size_t)255; };
  size_t o = 0;
  __hip_bfloat16* h2s = (__hip_bfloat16*)(w + o); o += al(E_pad * 128 * 2);
  __hip_bfloat16* W2s = (__hip_bfloat16*)(w + o); o += al((size_t)128 * 3072 * 2);
  float* featb = (float*)(w + o);                 o += al(E_pad * 48 * 4);
  int* head  = (int*)(w + o);                     o += al((size_t)n_dst * 4);
  int* nxt   = (int*)(w + o);                     o += al((size_t)E * 4);

  hipMemsetAsync(head, 0xFF, (size_t)n_dst * 4, stream);   // head = -1

  const int NW = (128 * WNUMEL / 4) / 256;        // 384 vectorized w2s blocks
  const int NM = (E + 7) / 8;                     // mlp blocks
  const int NL = (E + 255) / 256;                 // list-build blocks
  k_pre<<<NW + NM + NL, 256, 0, stream>>>(W2, W2s, edge_scalars, W1, b1, h2s,
                                          dst_idx, head, nxt, E, NW, NM);
  dim3 gg(nblk64, 3);
  k_gemm<<<gg, 256, 0, stream>>>((const u16*)h2s, (const u16*)W2s, h_src, src_idx,
                                 b2, featb, E);
  k_gather<<<(n_dst + 3) / 4, 256, 0, stream>>>(featb, edge_vec, head, nxt,
                                                (float*)d_out, n_dst);
}

// Round 14
// 79.625 us; speedup vs baseline: 1.8377x; 1.8377x over previous
//
#include <hip/hip_runtime.h>
#include <hip/hip_bf16.h>

typedef unsigned short u16;
typedef __attribute__((ext_vector_type(8))) short short8;
typedef __attribute__((ext_vector_type(4))) float f32x4;

#define HID 128
#define WNUMEL 3072
#define OUTD 144

// ---------- fused pre-pass: W2 swizzle | MFMA-MLP | sh + linked-list build ----------
__global__ void k_pre(const float* __restrict__ W2, __hip_bfloat16* __restrict__ W2s,
                      const float* __restrict__ es, const float* __restrict__ W1,
                      const float* __restrict__ b1, __hip_bfloat16* __restrict__ h2s,
                      const float* __restrict__ ev, const int* __restrict__ dst,
                      float* __restrict__ shb, int* __restrict__ head,
                      int* __restrict__ nxt, int E, int NW, int NM) {
  __shared__ u16 wlds[4096];           // 8 KB: W1 B-fragments (MLP branch only)
  const int b = blockIdx.x, tid = threadIdx.x;
  if (b < NW) {
    // W2 swizzle, coalesced READ side: f = k*3072+n, scatter-write bf16
    int f = b * 256 + tid;                            // < 128*3072
    int k = f / WNUMEL, n = f - k * WNUMEL;
    int s = k >> 5, h = (k >> 3) & 3, i = k & 7;
    int tt = n >> 4, c = n & 15;
    W2s[((size_t)(tt * 4 + s) * 64 + (c + 16 * h)) * 8 + i] = __float2bfloat16(W2[f]);
  } else if (b < NW + NM) {
    // MLP via MFMA: h2 = silu(es@W1+b1)*0.125 -> h2s fragment layout.
    // 64 edges/block; wave w owns edge-tile mt=w. A/B k-bijection matches the
    // main GEMM convention: k = 8*((lane>>4)&3) + i (s=0, K=32 exact).
    const int e0 = (b - NW) * 64;
    const int w = tid >> 6, l = tid & 63;
    const int c = l & 15, kb = 8 * ((l >> 4) & 3);
    // stage W1 fragments (wave w does nt = 2w, 2w+1)
#pragma unroll
    for (int q = 0; q < 2; ++q) {
      int nt = 2 * w + q;
      int n = nt * 16 + c;
#pragma unroll
      for (int i = 0; i < 8; ++i)
        wlds[(nt * 64 + l) * 8 + i] = (u16)__bfloat16_as_ushort(
            __float2bfloat16(W1[(kb + i) * HID + n]));
    }
    // es A-fragment for this wave's 16 edges
    short8 ef = {0, 0, 0, 0, 0, 0, 0, 0};
    {
      int e = e0 + w * 16 + c;
      if (e < E) {
        const float4 p0 = *(const float4*)(es + (size_t)e * 32 + kb);
        const float4 p1 = *(const float4*)(es + (size_t)e * 32 + kb + 4);
        u16* pe = (u16*)&ef;
#pragma unroll
        for (int i = 0; i < 4; ++i) {
          pe[i]     = __bfloat16_as_ushort(__float2bfloat16((&p0.x)[i]));
          pe[4 + i] = __bfloat16_as_ushort(__float2bfloat16((&p1.x)[i]));
        }
      }
    }
    __syncthreads();
#pragma unroll
    for (int nt = 0; nt < 8; ++nt) {
      short8 bf = *(const short8*)(wlds + (nt * 64 + l) * 8);
      float b1v = b1[nt * 16 + c];
      f32x4 acc = {b1v, b1v, b1v, b1v};
      acc = __builtin_amdgcn_mfma_f32_16x16x32_bf16(ef, bf, acc, 0, 0, 0);
      // C layout: col = lane&15 (h_lo), row = (lane>>4)*4+j (e_lo)
      int hh = (2 * nt + (c >> 3)) & 3;
      int s = nt >> 1;
      int i = c & 7;
#pragma unroll
      for (int j = 0; j < 4; ++j) {
        int e = e0 + w * 16 + (l >> 4) * 4 + j;
        if (e < E) {
          float a = acc[j];
          float z = a / (1.f + expf(-a)) * 0.125f;    // silu, fold 1/sqrt(64)
          h2s[((size_t)(e >> 4) * 4 + s) * 512 + ((e & 15) + 16 * hh) * 8 + i] =
              __float2bfloat16(z);
        }
      }
    }
  } else {
    int e = (b - NW - NM) * 256 + tid;
    if (e >= E) return;
    float vx = ev[e * 3 + 0], vy = ev[e * 3 + 1], vz = ev[e * 3 + 2];
    float nrm = fmaxf(sqrtf(vx * vx + vy * vy + vz * vz), 1e-9f);
    float x = vx / nrm, y = vy / nrm, z = vz / nrm;
    const float SQ3 = 1.7320508075688772f, SQ5 = 2.2360679774997896f,
                SQ15 = 3.872983346207417f;
    float* sp = shb + (size_t)e * 9;
    sp[0] = 1.f;
    sp[1] = SQ3 * x; sp[2] = SQ3 * y; sp[3] = SQ3 * z;
    sp[4] = SQ15 * x * y; sp[5] = SQ15 * y * z;
    sp[6] = 0.5f * SQ5 * (3.f * z * z - 1.f);
    sp[7] = SQ15 * x * z;
    sp[8] = 0.5f * SQ15 * (x * x - y * y);
    nxt[e] = atomicExch(&head[dst[e]], e);           // per-dst linked list
  }
}

// ---------- fused GEMM + x-contraction -> feat[E][48]  (R10 champion, verbatim) ----------
__global__ __launch_bounds__(256, 2) void k_gemm(
    const u16* __restrict__ h2s, const u16* __restrict__ W2s,
    const float* __restrict__ hsrc, const int* __restrict__ srci,
    const float* __restrict__ b2, float* __restrict__ feat_out, int E) {
  __shared__ float lds[4160];          // xT[64u][64e] (16KB), then fl[4][1040]
  float* xT = lds;
  float* fl = lds;
  const int tid = threadIdx.x, lane = tid & 63, wave = tid >> 6;
  const int blk = blockIdx.x, l3 = blockIdx.y;
  const int c = lane & 15, g = lane >> 4;

  // stage x transposed (wave w stages u-rows [w*16, w*16+16))
  {
    int e = lane, u0 = wave * 16;
    int eg = min(blk * 64 + e, E - 1);
    const float* xr = hsrc + (size_t)srci[eg] * 64 + u0;
#pragma unroll
    for (int k = 0; k < 16; ++k) xT[(u0 + k) * 64 + e] = xr[k];
  }
  // A fragments: 4 M-tiles x 4 k-steps
  short8 af[4][4];
#pragma unroll
  for (int mt = 0; mt < 4; ++mt)
#pragma unroll
    for (int s = 0; s < 4; ++s)
      af[mt][s] = *(const short8*)(h2s + ((size_t)((blk * 4 + mt) * 4 + s) * 64 + lane) * 8);
  __syncthreads();

  float feat[4][4] = {};               // [mt][j], this l-path, this wave's u-range
  const int T0 = l3 * 64 + wave * 16;
  const u16* Bg = W2s + (size_t)T0 * 2048;
  const float* b2g = b2 + T0 * 16 + c;

#pragma unroll
  for (int k = 0; k < 16; ++k) {       // wave's 16 N-tiles, no barriers
    short8 bf[4];
#pragma unroll
    for (int s = 0; s < 4; ++s)
      bf[s] = *(const short8*)(Bg + ((size_t)(k * 4 + s) * 64 + lane) * 8);
    float b2v = 0.125f * b2g[k * 16];
#pragma unroll
    for (int mt = 0; mt < 4; ++mt) {
      f32x4 acc = {b2v, b2v, b2v, b2v};
#pragma unroll
      for (int s = 0; s < 4; ++s)
        acc = __builtin_amdgcn_mfma_f32_16x16x32_bf16(af[mt][s], bf[s], acc, 0, 0, 0);
      const float4 xv = *(const float4*)&xT[(wave * 16 + k) * 64 + mt * 16 + g * 4];
#pragma unroll
      for (int j = 0; j < 4; ++j)
        feat[mt][j] = fmaf((&xv.x)[j], acc[j], feat[mt][j]);
    }
  }

  // cross-wave feat reduction in LDS (reuses xT space — barrier first)
  __syncthreads();
#pragma unroll
  for (int mt = 0; mt < 4; ++mt)
#pragma unroll
    for (int j = 0; j < 4; ++j)
      fl[wave * 1040 + (mt * 16 + g * 4 + j) * 16 + c] = feat[mt][j];
  __syncthreads();

  // epilogue: sum the 4 wave-partials, store compact feat slice for this l3
#pragma unroll
  for (int r = 0; r < 4; ++r) {
    int p = r * 256 + tid;             // 1024 = 64 edges x 16 v
    int eloc = p >> 4, v = p & 15;
    float f = fl[p] + fl[1040 + p] + fl[2080 + p] + fl[3120 + p];
    int e = blk * 64 + eloc;
    if (e < E) feat_out[(size_t)e * 48 + l3 * 16 + v] = f;
  }
}

// ---------- gather: one wave per dst; walk linked list; apply sh; mean ----------
__global__ void k_gather(const float* __restrict__ feat, const float* __restrict__ shb,
                         const int* __restrict__ head, const int* __restrict__ nxt,
                         float* __restrict__ out, int n_dst) {
  int d = blockIdx.x * 4 + (threadIdx.x >> 6);
  int lane = threadIdx.x & 63;
  if (d >= n_dst) return;
  int fi[4], si[4];
#pragma unroll
  for (int r = 0; r < 4; ++r) {
    int o = lane * 4 + r;
    if (o < 16)      { fi[r] = o;                 si[r] = 0; }        // sh[0] == 1
    else if (o < 64) { int id = o - 16; fi[r] = 16 + id / 3; si[r] = 1 + id % 3; }
    else             { int id = o - 64; fi[r] = 32 + id / 5; si[r] = 4 + id % 5; }
  }
  int e = head[d];                     // same addr across lanes -> broadcast load
  float4 acc = {0.f, 0.f, 0.f, 0.f};
  int deg = 0;
  while (e >= 0) {
    int en = nxt[e];                   // issue next-pointer first (chase overlap)
    if (lane < 36) {
      const float* fp = feat + (size_t)e * 48;
      const float* sp = shb + (size_t)e * 9;
#pragma unroll
      for (int r = 0; r < 4; ++r)
        (&acc.x)[r] = fmaf(fp[fi[r]], sp[si[r]], (&acc.x)[r]);
    }
    ++deg;
    e = en;
  }
  if (lane < 36) {
    float inv = 1.f / (float)max(deg, 1);
    acc.x *= inv; acc.y *= inv; acc.z *= inv; acc.w *= inv;
    *(float4*)&out[(size_t)d * OUTD + lane * 4] = acc;
  }
}

extern "C" void kernel_launch(void* const* d_in, const int* in_sizes, int n_in,
                              void* d_out, int out_size, void* d_ws, size_t ws_size,
                              hipStream_t stream) {
  const float* h_src        = (const float*)d_in[0];
  const float* edge_vec     = (const float*)d_in[1];
  const float* edge_scalars = (const float*)d_in[2];
  const float* W1           = (const float*)d_in[3];
  const float* b1           = (const float*)d_in[4];
  const float* W2           = (const float*)d_in[5];
  const float* b2           = (const float*)d_in[6];
  const int*   src_idx      = (const int*)d_in[7];
  const int*   dst_idx      = (const int*)d_in[8];

  const int E = in_sizes[1] / 3;
  const int n_dst = out_size / OUTD;
  const int nblk64 = (E + 63) / 64;
  const size_t E_pad = (size_t)nblk64 * 64;

  char* w = (char*)d_ws;
  auto al = [](size_t x) { return (x + 255) & ~(size_t)255; };
  size_t o = 0;
  float* shb = (float*)(w + o);                   o += al(E_pad * 9 * 4);
  __hip_bfloat16* h2s = (__hip_bfloat16*)(w + o); o += al(E_pad * 128 * 2);
  __hip_bfloat16* W2s = (__hip_bfloat16*)(w + o); o += al((size_t)128 * 3072 * 2);
  float* featb = (float*)(w + o);                 o += al(E_pad * 48 * 4);
  int* head  = (int*)(w + o);                     o += al((size_t)n_dst * 4);
  int* nxt   = (int*)(w + o);                     o += al((size_t)E * 4);

  hipMemsetAsync(head, 0xFF, (size_t)n_dst * 4, stream);   // head = -1

  const int NW = (128 * WNUMEL) / 256;            // 1536 w2s blocks
  const int NM = (E + 63) / 64;                   // mfma-mlp blocks (64 edges each)
  const int NL = (E + 255) / 256;                 // sh + list blocks
  k_pre<<<NW + NM + NL, 256, 0, stream>>>(W2, W2s, edge_scalars, W1, b1, h2s,
                                          edge_vec, dst_idx, shb, head, nxt, E, NW, NM);
  dim3 gg(nblk64, 3);
  k_gemm<<<gg, 256, 0, stream>>>((const u16*)h2s, (const u16*)W2s, h_src, src_idx,
                                 b2, featb, E);
  k_gather<<<(n_dst + 3) / 4, 256, 0, stream>>>(featb, shb, head, nxt,
                                                (float*)d_out, n_dst);
}